// Round 1
// 418.972 us; speedup vs baseline: 1.0914x; 1.0914x over previous
//
#include <hip/hip_runtime.h>
#include <cstddef>
#include <cstdint>

#define B_  32
#define S_  50
#define L_  20
#define R_  16
#define D_  100
#define V_  50000
#define T_  320       // L_*R_
#define RD_ 1600      // R_*D_
#define BS_ 1600      // B_*S_
#define NG_ 25        // sign-table groups (4 bits each)
#define NP_ 16        // patterns per group

typedef float v4f __attribute__((ext_vector_type(4)));
typedef unsigned v2u __attribute__((ext_vector_type(2)));
typedef unsigned short u16;
#define NTL(p)  __builtin_nontemporal_load((const v4f*)(p))
#define NTL8(p) __builtin_nontemporal_load((const v2u*)(p))

__device__ __forceinline__ float uf(unsigned u) { return __uint_as_float(u); }

// split fp32 into bf16 hi (truncate) + bf16 lo (residual); hi+lo ~ a to 2^-16 rel
__device__ __forceinline__ void bsplit(float a, unsigned& h, unsigned& l) {
  const unsigned bits = __float_as_uint(a);
  const unsigned hb = bits & 0xffff0000u;
  h = hb >> 16;
  l = __float_as_uint(a - __uint_as_float(hb)) >> 16;
}

// ---------------- fused setup:
// blocks [0,1600): x[bs][j] = sum_l emb0[stories]*in_mult -> bf16 hi/lo planes
// blocks [1600,2000): sign table from U (4-bit)
// blocks [2000,2200): vkeys (8 waves -> 8 j's per block)
// blocks [2200,2400): u0 = U @ init_state
// blocks [2400,3025): Ww -> bf16 hi/lo planes (8 elems/thread)
__global__ __launch_bounds__(512) void setup_kernel(
    const int* __restrict__ stories, const float* __restrict__ emb,
    const float* __restrict__ in_mult, const float* __restrict__ U,
    const float* __restrict__ Vw, const float* __restrict__ keys,
    const float* __restrict__ init_state, const float* __restrict__ Ww,
    u16* __restrict__ xh, u16* __restrict__ xl,
    u16* __restrict__ wh, u16* __restrict__ wl,
    float* __restrict__ table, float* __restrict__ vk, float* __restrict__ u0)
{
  const int blk = blockIdx.x, tid = threadIdx.x;
  if (blk < 1600) {
    __shared__ int toks[T_];
    const int* st = stories + (size_t)blk * T_;
    if (tid < T_) toks[tid] = st[tid];
    __syncthreads();
    if (tid < 400) {
      const int j4 = tid * 4;
      const int r  = j4 / D_;
      const int d4 = j4 - r * D_;
      float4 acc = make_float4(0.f, 0.f, 0.f, 0.f);
      #pragma unroll
      for (int l = 0; l < 20; ++l) {
        const int t = r * 20 + l;
        const int tok = toks[t];
        if (tok != 0) {
          float4 e = *(const float4*)&emb[(size_t)tok * D_ + d4];
          float4 m = *(const float4*)&in_mult[(size_t)t * D_ + d4];
          acc.x += e.x * m.x; acc.y += e.y * m.y;
          acc.z += e.z * m.z; acc.w += e.w * m.w;
        }
      }
      unsigned h0,h1,h2,h3,l0,l1,l2,l3;
      bsplit(acc.x, h0, l0); bsplit(acc.y, h1, l1);
      bsplit(acc.z, h2, l2); bsplit(acc.w, h3, l3);
      v2u hv, lv;
      hv.x = h0 | (h1 << 16); hv.y = h2 | (h3 << 16);
      lv.x = l0 | (l1 << 16); lv.y = l2 | (l3 << 16);
      *(v2u*)&xh[(size_t)blk * RD_ + j4] = hv;
      *(v2u*)&xl[(size_t)blk * RD_ + j4] = lv;
    }
  } else if (blk < 2000) {
    const int q = blk - 1600;
    const int g = q >> 4, p = q & 15;
    const float s0 = (p & 1) ? -1.f : 1.f;
    const float s1 = (p & 2) ? -1.f : 1.f;
    const float s2 = (p & 4) ? -1.f : 1.f;
    const float s3 = (p & 8) ? -1.f : 1.f;
    if (tid < 400) {
      const int j4 = tid * 4;
      float t[4];
      #pragma unroll
      for (int jj = 0; jj < 4; ++jj) {
        const float* ur = &U[(size_t)(j4 + jj) * D_ + 4 * g];
        t[jj] = s0*ur[0] + s1*ur[1] + s2*ur[2] + s3*ur[3];
      }
      *(float4*)&table[((size_t)(g * NP_ + p)) * RD_ + j4] =
          make_float4(t[0], t[1], t[2], t[3]);
    }
  } else if (blk < 2200) {
    const int wave = tid >> 6, lane = tid & 63;
    const int j = (blk - 2000) * 8 + wave;
    float acc = 0.f;
    for (int k = lane; k < RD_; k += 64)
      acc += keys[k] * Vw[(size_t)j * RD_ + k];
    #pragma unroll
    for (int off = 32; off > 0; off >>= 1) acc += __shfl_down(acc, off);
    if (lane == 0) vk[j] = acc;
  } else if (blk < 2400) {
    const int wave = tid >> 6, lane = tid & 63;
    const int j = (blk - 2200) * 8 + wave;
    const float* Ur = U + (size_t)j * D_;
    float acc = Ur[lane] * init_state[lane];
    if (lane < 36) acc += Ur[64 + lane] * init_state[64 + lane];
    #pragma unroll
    for (int off = 32; off > 0; off >>= 1) acc += __shfl_down(acc, off);
    if (lane == 0) u0[j] = acc;
  } else {
    // Ww -> bf16 hi/lo: 625 blocks * 512 thr * 8 elems = 2,560,000
    const int e = ((blk - 2400) * 512 + tid) * 8;
    float4 a0 = *(const float4*)&Ww[e];
    float4 a1 = *(const float4*)&Ww[e + 4];
    unsigned h[8], l[8];
    bsplit(a0.x, h[0], l[0]); bsplit(a0.y, h[1], l[1]);
    bsplit(a0.z, h[2], l[2]); bsplit(a0.w, h[3], l[3]);
    bsplit(a1.x, h[4], l[4]); bsplit(a1.y, h[5], l[5]);
    bsplit(a1.z, h[6], l[6]); bsplit(a1.w, h[7], l[7]);
    uint4 hv = make_uint4(h[0]|(h[1]<<16), h[2]|(h[3]<<16),
                          h[4]|(h[5]<<16), h[6]|(h[7]<<16));
    uint4 lv = make_uint4(l[0]|(l[1]<<16), l[2]|(l[3]<<16),
                          l[4]|(l[5]<<16), l[6]|(l[7]<<16));
    *(uint4*)&wh[e] = hv;
    *(uint4*)&wl[e] = lv;
  }
}

// ---------------- bf16x3 MFMA GEMM: C[m][n] = sum_k x[m][k]*Ww[n][k]
// A,B given as bf16 hi/lo planes; acc fp32 via v_mfma_f32_16x16x32_bf16.
// 128x128 tile, BK=32, 4 waves (2x2), wave tile 64x64 (4x4 frags of 16x16),
// double-buffered LDS staged with global_load_lds(16B). Grid 13x13 (tail clamped).
typedef const __attribute__((address_space(1))) unsigned GAu;
typedef __attribute__((address_space(3))) unsigned LDSu;
#define GLL(SRC, DST) __builtin_amdgcn_global_load_lds((GAu*)(SRC), (LDSu*)(DST), 16, 0, 0)

__device__ __forceinline__ void mfma16(v4f& d, v4f a, v4f b) {
  asm("v_mfma_f32_16x16x32_bf16 %0, %1, %2, %0" : "+v"(d) : "v"(a), "v"(b));
}

__global__ __launch_bounds__(256) void gemm_mfma_kernel(
    const u16* __restrict__ xh, const u16* __restrict__ xl,
    const u16* __restrict__ wh, const u16* __restrict__ wl,
    float* __restrict__ C)
{
  // [buf][arr: Ah,Al,Bh,Bl][128 rows * 64B] = 64 KiB
  __shared__ __align__(16) char smem[2][4][8192];
  const int tid = threadIdx.x;
  const int lane = tid & 63, wid = tid >> 6;
  const int bm = blockIdx.y * 128, bn = blockIdx.x * 128;

  // staging geometry: chunk = wid*2+i covers rows [chunk*16, chunk*16+16)
  int ldsoff[2], srcA[2], srcB[2];
  #pragma unroll
  for (int i = 0; i < 2; ++i) {
    const int chunk = wid * 2 + i;
    const int row = chunk * 16 + (lane >> 2);
    const int kb = (lane & 3) * 16;          // byte offset within 64B k-row
    int ra = bm + row; if (ra > 1599) ra = 1599;   // tail clamp (stores guarded)
    int rb = bn + row; if (rb > 1599) rb = 1599;
    srcA[i] = ra * 3200 + kb;                // row stride 1600*2B
    srcB[i] = rb * 3200 + kb;
    ldsoff[i] = chunk * 1024;
  }
  const char* gxh = (const char*)xh;
  const char* gxl = (const char*)xl;
  const char* gwh = (const char*)wh;
  const char* gwl = (const char*)wl;

  // compute geometry: 2x2 waves, wave tile 64x64
  const int wm = wid >> 1, wn = wid & 1;
  const int r15 = lane & 15, q = lane >> 4;
  const int aoff = (wm * 64 + r15) * 64 + q * 16;
  const int boff = (wn * 64 + r15) * 64 + q * 16;

  v4f acc[4][4];
  #pragma unroll
  for (int i = 0; i < 4; ++i)
    #pragma unroll
    for (int j = 0; j < 4; ++j) acc[i][j] = (v4f)(0.f);

  auto stage = [&](int buf, int kt) {
    const int kb = kt * 64;                  // 32 bf16 = 64B per K-step
    #pragma unroll
    for (int i = 0; i < 2; ++i) {
      GLL(gxh + srcA[i] + kb, &smem[buf][0][ldsoff[i]]);
      GLL(gxl + srcA[i] + kb, &smem[buf][1][ldsoff[i]]);
      GLL(gwh + srcB[i] + kb, &smem[buf][2][ldsoff[i]]);
      GLL(gwl + srcB[i] + kb, &smem[buf][3][ldsoff[i]]);
    }
  };

  stage(0, 0);
  __syncthreads();

  for (int kt = 0; kt < 50; ++kt) {
    const int cur = kt & 1;
    if (kt < 49) stage(cur ^ 1, kt + 1);
    const char* s0 = &smem[cur][0][0];
    v4f ah[4], al[4], bh[4], bl[4];
    #pragma unroll
    for (int t = 0; t < 4; ++t) {
      ah[t] = *(const v4f*)(s0 +         aoff + t * 1024);
      al[t] = *(const v4f*)(s0 +  8192 + aoff + t * 1024);
      bh[t] = *(const v4f*)(s0 + 16384 + boff + t * 1024);
      bl[t] = *(const v4f*)(s0 + 24576 + boff + t * 1024);
    }
    #pragma unroll
    for (int im = 0; im < 4; ++im)
      #pragma unroll
      for (int in = 0; in < 4; ++in) {
        mfma16(acc[im][in], ah[im], bh[in]);   // hi*hi
        mfma16(acc[im][in], ah[im], bl[in]);   // hi*lo
        mfma16(acc[im][in], al[im], bh[in]);   // lo*hi
      }
    __syncthreads();
  }

  // C/D layout: col = lane&15, row = (lane>>4)*4 + reg
  const int mb  = bm + wm * 64 + q * 4;
  const int nbq = bn + wn * 64 + r15;
  #pragma unroll
  for (int im = 0; im < 4; ++im) {
    #pragma unroll
    for (int in = 0; in < 4; ++in) {
      const int n = nbq + in * 16;
      const int m0 = mb + im * 16;
      if (n < 1600) {
        #pragma unroll
        for (int r = 0; r < 4; ++r)
          if (m0 + r < 1600)
            C[(size_t)(m0 + r) * 1600 + n] = acc[im][in][r];
      }
    }
  }
}

// ---------------- scan + fused head: one block per b.
// x consumed as bf16 hi/lo planes (sent = hi+lo); Wall fp32.
__global__ __launch_bounds__(512, 2) void scan_kernel(
    const u16* __restrict__ xh,        // [BS_][RD_] bf16 hi
    const u16* __restrict__ xl,        // [BS_][RD_] bf16 lo
    const float* __restrict__ Wall,    // [BS_][RD_]
    const float* __restrict__ table,   // [NG_*NP_][RD_]
    const float* __restrict__ u0,      // [RD_]
    const float* __restrict__ vkeys,   // [RD_]
    const float* __restrict__ keys,    // [RD_]
    const float* __restrict__ init_state, // [D_]
    const float* __restrict__ alpha_in_p,
    const int*   __restrict__ queries, // [B_][L_]
    const float* __restrict__ emb,     // [V_][D_]
    const float* __restrict__ q_mult,  // [L_][D_]
    const float* __restrict__ Hw,      // [D_][D_]
    const float* __restrict__ alpha_q_p,
    float* __restrict__ h_g)           // [B_][D_]
{
  const int b = blockIdx.x, tid = threadIdx.x;
  __shared__ __align__(16) float s_state[D_];
  __shared__ __align__(16) float s_c[RD_];
  __shared__ float s_hw[D_ * 101];     // Hw padded stride 101 (conflict-free)
  __shared__ unsigned long long s_mask[2];
  const float alpha = alpha_in_p[0];
  const bool active = (tid < 400);
  const int j4 = tid * 4;
  const int d4 = (j4 % D_);
  float4 kk = make_float4(0.f,0.f,0.f,0.f), vv = kk;
  const u16*   xhb = xh   + (size_t)b * S_ * RD_;
  const u16*   xlb = xl   + (size_t)b * S_ * RD_;
  const float* wb  = Wall + (size_t)b * S_ * RD_;
  v2u bxh[5], bxl[5]; v4f bw[5];
  #pragma unroll
  for (int i = 0; i < 5; ++i) { bxh[i] = (v2u)(0u); bxl[i] = (v2u)(0u); bw[i] = (v4f)(0.f); }
  if (active) {
    kk = *(const float4*)&keys[j4];
    vv = *(const float4*)&vkeys[j4];
    #pragma unroll
    for (int i = 0; i < 5; ++i) {          // preload steps 0..4 (non-temporal)
      bxh[i] = NTL8(&xhb[(size_t)i * RD_ + j4]);
      bxl[i] = NTL8(&xlb[(size_t)i * RD_ + j4]);
      bw[i]  = NTL(&wb[(size_t)i * RD_ + j4]);
    }
  }
  if (tid < D_) s_state[tid] = init_state[tid];
  __syncthreads();

  for (int sg = 0; sg < S_; sg += 5) {
    #pragma unroll
    for (int i = 0; i < 5; ++i) {
      const int s = sg + i;
      if (active) {
        const v2u hxv = bxh[i], lxv = bxl[i];
        const v4f w = bw[i];
        if (s + 5 < S_) {                  // stagger: prefetch step s+5
          bxh[i] = NTL8(&xhb[(size_t)(s + 5) * RD_ + j4]);
          bxl[i] = NTL8(&xlb[(size_t)(s + 5) * RD_ + j4]);
          bw[i]  = NTL(&wb[(size_t)(s + 5) * RD_ + j4]);
        }
        v4f sent;
        sent.x = uf(hxv.x << 16)          + uf(lxv.x << 16);
        sent.y = uf(hxv.x & 0xffff0000u)  + uf(lxv.x & 0xffff0000u);
        sent.z = uf(hxv.y << 16)          + uf(lxv.y << 16);
        sent.w = uf(hxv.y & 0xffff0000u)  + uf(lxv.y & 0xffff0000u);
        v4f u;
        if (s == 0) {
          float4 t0 = *(const float4*)&u0[j4];
          u.x = t0.x; u.y = t0.y; u.z = t0.z; u.w = t0.w;
        } else {
          u = (v4f)(0.f);
          const unsigned long long m0 = s_mask[0];
          const unsigned long long m1 = s_mask[1];
          #pragma unroll
          for (int g = 0; g < NG_; ++g) {
            const unsigned idx = (g < 16)
                ? (unsigned)((m0 >> (4 * g)) & 15ull)
                : (unsigned)((m1 >> (4 * g - 64)) & 15ull);
            float4 tv = *(const float4*)&table[((size_t)(g * NP_) + idx) * RD_ + j4];
            u.x += tv.x; u.y += tv.y; u.z += tv.z; u.w += tv.w;
          }
        }
        float4 sd = *(const float4*)&s_state[d4];
        float zx = sent.x * sd.x + sent.x * kk.x;
        float zy = sent.y * sd.y + sent.y * kk.y;
        float zz = sent.z * sd.z + sent.z * kk.z;
        float zw = sent.w * sd.w + sent.w * kk.w;
        float gx = 1.0f / (1.0f + expf(-zx));
        float gy = 1.0f / (1.0f + expf(-zy));
        float gz = 1.0f / (1.0f + expf(-zz));
        float gw = 1.0f / (1.0f + expf(-zw));
        float cx = u.x + vv.x + w.x; cx = cx >= 0.f ? cx : alpha * cx;
        float cy = u.y + vv.y + w.y; cy = cy >= 0.f ? cy : alpha * cy;
        float cz = u.z + vv.z + w.z; cz = cz >= 0.f ? cz : alpha * cz;
        float cw = u.w + vv.w + w.w; cw = cw >= 0.f ? cw : alpha * cw;
        v4f cc;
        cc.x = (gx == 0.5f) ? 0.f : cx * gx;
        cc.y = (gy == 0.5f) ? 0.f : cy * gy;
        cc.z = (gz == 0.5f) ? 0.f : cz * gz;
        cc.w = (gw == 0.5f) ? 0.f : cw * gw;
        *(v4f*)&s_c[j4] = cc;
      }
      __syncthreads();
      if (tid < D_) {
        float csum = 0.f;
        #pragma unroll
        for (int r = 0; r < R_; ++r) csum += s_c[r * D_ + tid];
        float v = s_state[tid] + csum;
        v = v / sqrtf(v * v);   // faithful: torch.norm over singleton dim -> sign
        s_state[tid] = v;
        unsigned long long mask = __ballot(v < 0.f);
        if ((tid & 63) == 0) s_mask[tid >> 6] = mask;
      }
      __syncthreads();
    }
  }

  // ---- fused head: h[b][d] = prelu(q[b][d] + dot(state, Hw[d]), alpha_q)
  for (int f = tid; f < D_ * D_; f += 512) {
    const int row = f / D_, col = f - row * D_;
    s_hw[row * 101 + col] = Hw[f];
  }
  __syncthreads();
  if (tid < D_) {
    float q = 0.f;
    #pragma unroll
    for (int l = 0; l < L_; ++l) {
      const int tok = queries[b * L_ + l];
      if (tok != 0) q += emb[(size_t)tok * D_ + tid] * q_mult[l * D_ + tid];
    }
    float a = 0.f;
    #pragma unroll 4
    for (int k = 0; k < D_; ++k) a += s_state[k] * s_hw[tid * 101 + k];
    float h = q + a;
    const float aq = alpha_q_p[0];
    h = h >= 0.f ? h : aq * h;
    h_g[(size_t)b * D_ + tid] = h;
  }
}

// ---------------- out[b][v] = sum_k h[b][k] * Rw[v][k]   (v-tile=32 staged in LDS)
__global__ __launch_bounds__(256) void out_kernel(
    const float* __restrict__ h_g, const float* __restrict__ Rw, float* __restrict__ out)
{
  __shared__ __align__(16) float sh[B_ * D_];    // 3200
  __shared__ __align__(16) float sr[32 * D_];    // 3200
  int tid = threadIdx.x;
  int v0 = blockIdx.x * 32;
  for (int i = tid; i < B_ * D_; i += 256) sh[i] = h_g[i];
  int nrows = V_ - v0; if (nrows > 32) nrows = 32;
  for (int i = tid; i < nrows * D_; i += 256) sr[i] = Rw[(size_t)v0 * D_ + i];
  __syncthreads();
  const float4* sh4 = (const float4*)sh;
  const float4* sr4 = (const float4*)sr;
  int tv = (tid & 15) * 2;
  int tb = (tid >> 4) * 2;
  float a00 = 0.f, a01 = 0.f, a10 = 0.f, a11 = 0.f;
  #pragma unroll
  for (int kc = 0; kc < 25; ++kc) {
    float4 h0 = sh4[tb * 25 + kc];
    float4 h1 = sh4[(tb + 1) * 25 + kc];
    float4 r0 = sr4[tv * 25 + kc];
    float4 r1 = sr4[(tv + 1) * 25 + kc];
    a00 += h0.x*r0.x + h0.y*r0.y + h0.z*r0.z + h0.w*r0.w;
    a01 += h0.x*r1.x + h0.y*r1.y + h0.z*r1.z + h0.w*r1.w;
    a10 += h1.x*r0.x + h1.y*r0.y + h1.z*r0.z + h1.w*r0.w;
    a11 += h1.x*r1.x + h1.y*r1.y + h1.z*r1.z + h1.w*r1.w;
  }
  if (tv < nrows) {
    out[(size_t)tb * V_ + v0 + tv] = a00;
    out[(size_t)(tb + 1) * V_ + v0 + tv] = a10;
  }
  if (tv + 1 < nrows) {
    out[(size_t)tb * V_ + v0 + tv + 1] = a01;
    out[(size_t)(tb + 1) * V_ + v0 + tv + 1] = a11;
  }
}

extern "C" void kernel_launch(void* const* d_in, const int* in_sizes, int n_in,
                              void* d_out, int out_size, void* d_ws, size_t ws_size,
                              hipStream_t stream) {
  const int*   stories    = (const int*)  d_in[0];
  const int*   queries    = (const int*)  d_in[1];
  const float* emb        = (const float*)d_in[2];
  const float* in_mult    = (const float*)d_in[3];
  const float* q_mult     = (const float*)d_in[4];
  const float* keys       = (const float*)d_in[5];
  const float* init_state = (const float*)d_in[6];
  const float* U          = (const float*)d_in[7];
  const float* Vw         = (const float*)d_in[8];
  const float* Ww         = (const float*)d_in[9];
  const float* Hw         = (const float*)d_in[10];
  const float* Rw         = (const float*)d_in[11];
  const float* alpha_in   = (const float*)d_in[12];
  const float* alpha_q    = (const float*)d_in[13];
  float* out = (float*)d_out;

  char* ws = (char*)d_ws;
  u16*   xh    = (u16*)  (ws);               //  5,120,000 B (bf16 hi of x)
  u16*   xl    = (u16*)  (ws +  5120000);    //  5,120,000 B (bf16 lo of x)
  float* Wall  = (float*)(ws + 10240000);    // 10,240,000 B
  float* table = (float*)(ws + 20480000);    //  2,560,000 B (25*16*1600*4)
  u16*   wwh   = (u16*)  (ws + 23040000);    //  5,120,000 B (bf16 hi of Ww)
  u16*   wwl   = (u16*)  (ws + 28160000);    //  5,120,000 B (bf16 lo of Ww)
  float* vk    = (float*)(ws + 33280000);    //      6,400 B
  float* u0    = (float*)(ws + 33286400);    //      6,400 B
  float* hbuf  = (float*)(ws + 33292800);    //     12,800 B
  // total 33,305,600 B (identical footprint to previous version)

  setup_kernel<<<3025, 512, 0, stream>>>(stories, emb, in_mult, U, Vw, keys,
                                         init_state, Ww, xh, xl, wwh, wwl,
                                         table, vk, u0);
  gemm_mfma_kernel<<<dim3(13, 13), 256, 0, stream>>>(xh, xl, wwh, wwl, Wall);
  scan_kernel<<<B_, 512, 0, stream>>>(xh, xl, Wall, table, u0, vk, keys,
                                      init_state, alpha_in, queries, emb,
                                      q_mult, Hw, alpha_q, hbuf);
  out_kernel<<<(V_ + 31) / 32, 256, 0, stream>>>(hbuf, Rw, out);
}

// Round 2
// 386.263 us; speedup vs baseline: 1.1838x; 1.0847x over previous
//
#include <hip/hip_runtime.h>
#include <cstddef>
#include <cstdint>

#define B_  32
#define S_  50
#define L_  20
#define R_  16
#define D_  100
#define V_  50000
#define T_  320       // L_*R_
#define RD_ 1600      // R_*D_
#define BS_ 1600      // B_*S_
#define NG_ 25        // sign-table groups (4 bits each)
#define NP_ 16        // patterns per group

typedef float v4f __attribute__((ext_vector_type(4)));
typedef unsigned short u16;
#define NTL(p)  __builtin_nontemporal_load((const v4f*)(p))

__device__ __forceinline__ float uf(unsigned u) { return __uint_as_float(u); }

// split fp32 into bf16 hi (truncate) + bf16 lo (residual); hi+lo ~ a to 2^-16 rel
__device__ __forceinline__ void bsplit(float a, unsigned& h, unsigned& l) {
  const unsigned bits = __float_as_uint(a);
  const unsigned hb = bits & 0xffff0000u;
  h = hb >> 16;
  l = __float_as_uint(a - __uint_as_float(hb)) >> 16;
}

__device__ __forceinline__ void bsplit4(float4 a, uint2& h, uint2& l) {
  unsigned h0,h1,h2,h3,l0,l1,l2,l3;
  bsplit(a.x, h0, l0); bsplit(a.y, h1, l1);
  bsplit(a.z, h2, l2); bsplit(a.w, h3, l3);
  h.x = h0 | (h1 << 16); h.y = h2 | (h3 << 16);
  l.x = l0 | (l1 << 16); l.y = l2 | (l3 << 16);
}

// ---------------- fused setup:
// blocks [0,1600): x[bs][j] = sum_l emb0[stories]*in_mult   (fp32, scan-friendly)
// blocks [1600,2000): sign table from U (4-bit)
// blocks [2000,2200): vkeys (8 waves -> 8 j's per block)
// blocks [2200,2400): u0 = U @ init_state
// blocks [2400,3025): Ww -> bf16 hi/lo planes (8 elems/thread)
__global__ __launch_bounds__(512) void setup_kernel(
    const int* __restrict__ stories, const float* __restrict__ emb,
    const float* __restrict__ in_mult, const float* __restrict__ U,
    const float* __restrict__ Vw, const float* __restrict__ keys,
    const float* __restrict__ init_state, const float* __restrict__ Ww,
    float* __restrict__ x,
    u16* __restrict__ wh, u16* __restrict__ wl,
    float* __restrict__ table, float* __restrict__ vk, float* __restrict__ u0)
{
  const int blk = blockIdx.x, tid = threadIdx.x;
  if (blk < 1600) {
    __shared__ int toks[T_];
    const int* st = stories + (size_t)blk * T_;
    if (tid < T_) toks[tid] = st[tid];
    __syncthreads();
    if (tid < 400) {
      const int j4 = tid * 4;
      const int r  = j4 / D_;
      const int d4 = j4 - r * D_;
      float4 acc = make_float4(0.f, 0.f, 0.f, 0.f);
      #pragma unroll
      for (int l = 0; l < 20; ++l) {
        const int t = r * 20 + l;
        const int tok = toks[t];
        if (tok != 0) {
          float4 e = *(const float4*)&emb[(size_t)tok * D_ + d4];
          float4 m = *(const float4*)&in_mult[(size_t)t * D_ + d4];
          acc.x += e.x * m.x; acc.y += e.y * m.y;
          acc.z += e.z * m.z; acc.w += e.w * m.w;
        }
      }
      *(float4*)&x[(size_t)blk * RD_ + j4] = acc;
    }
  } else if (blk < 2000) {
    const int q = blk - 1600;
    const int g = q >> 4, p = q & 15;
    const float s0 = (p & 1) ? -1.f : 1.f;
    const float s1 = (p & 2) ? -1.f : 1.f;
    const float s2 = (p & 4) ? -1.f : 1.f;
    const float s3 = (p & 8) ? -1.f : 1.f;
    if (tid < 400) {
      const int j4 = tid * 4;
      float t[4];
      #pragma unroll
      for (int jj = 0; jj < 4; ++jj) {
        const float* ur = &U[(size_t)(j4 + jj) * D_ + 4 * g];
        t[jj] = s0*ur[0] + s1*ur[1] + s2*ur[2] + s3*ur[3];
      }
      *(float4*)&table[((size_t)(g * NP_ + p)) * RD_ + j4] =
          make_float4(t[0], t[1], t[2], t[3]);
    }
  } else if (blk < 2200) {
    const int wave = tid >> 6, lane = tid & 63;
    const int j = (blk - 2000) * 8 + wave;
    float acc = 0.f;
    for (int k = lane; k < RD_; k += 64)
      acc += keys[k] * Vw[(size_t)j * RD_ + k];
    #pragma unroll
    for (int off = 32; off > 0; off >>= 1) acc += __shfl_down(acc, off);
    if (lane == 0) vk[j] = acc;
  } else if (blk < 2400) {
    const int wave = tid >> 6, lane = tid & 63;
    const int j = (blk - 2200) * 8 + wave;
    const float* Ur = U + (size_t)j * D_;
    float acc = Ur[lane] * init_state[lane];
    if (lane < 36) acc += Ur[64 + lane] * init_state[64 + lane];
    #pragma unroll
    for (int off = 32; off > 0; off >>= 1) acc += __shfl_down(acc, off);
    if (lane == 0) u0[j] = acc;
  } else {
    // Ww -> bf16 hi/lo: 625 blocks * 512 thr * 8 elems = 2,560,000
    const int e = ((blk - 2400) * 512 + tid) * 8;
    float4 a0 = *(const float4*)&Ww[e];
    float4 a1 = *(const float4*)&Ww[e + 4];
    uint2 h0, l0, h1, l1;
    bsplit4(a0, h0, l0);
    bsplit4(a1, h1, l1);
    uint4 hv = make_uint4(h0.x, h0.y, h1.x, h1.y);
    uint4 lv = make_uint4(l0.x, l0.y, l1.x, l1.y);
    *(uint4*)&wh[e] = hv;
    *(uint4*)&wl[e] = lv;
  }
}

// ---------------- bf16x3 MFMA GEMM: Wall[m][n] = sum_k x[m][k]*Ww[n][k]
// A: fp32 x, reg-staged + in-kernel bf16 hi/lo split -> LDS.
// B: pre-converted bf16 planes staged with global_load_lds(16B).
// 128x128 tile, BK=32, 4 waves (2x2), wave tile 64x64, double-buffered LDS.
typedef const __attribute__((address_space(1))) unsigned GAu;
typedef __attribute__((address_space(3))) unsigned LDSu;
#define GLL(SRC, DST) __builtin_amdgcn_global_load_lds((GAu*)(SRC), (LDSu*)(DST), 16, 0, 0)

__device__ __forceinline__ void mfma16(v4f& d, v4f a, v4f b) {
  asm("v_mfma_f32_16x16x32_bf16 %0, %1, %2, %0" : "+v"(d) : "v"(a), "v"(b));
}

__global__ __launch_bounds__(256) void gemm_mfma_kernel(
    const float* __restrict__ A,
    const u16* __restrict__ wh, const u16* __restrict__ wl,
    float* __restrict__ C)
{
  // [buf][arr: Ah,Al,Bh,Bl][128 rows * 64B] = 64 KiB
  __shared__ __align__(16) char smem[2][4][8192];
  const int tid = threadIdx.x;
  const int lane = tid & 63, wid = tid >> 6;
  const int bm = blockIdx.y * 128, bn = blockIdx.x * 128;

  // ---- B staging geometry (global_load_lds): chunk covers 16 rows
  int ldsoff[2], srcB[2];
  #pragma unroll
  for (int i = 0; i < 2; ++i) {
    const int chunk = wid * 2 + i;
    const int row = chunk * 16 + (lane >> 2);
    const int kb = (lane & 3) * 16;          // byte offset within 64B k-row
    int rb = bn + row; if (rb > 1599) rb = 1599;   // tail clamp
    srcB[i] = rb * 3200 + kb;                // row stride 1600*2B
    ldsoff[i] = chunk * 1024;
  }
  const char* gwh = (const char*)wh;
  const char* gwl = (const char*)wl;

  // ---- A staging geometry (reg-staged fp32 -> bf16 split)
  // thread covers 4 segments: row = i*32 + tid>>3, kseg = tid&7 (4 fp32 each)
  int arow[4], awofs[4];
  const int akseg = tid & 7;
  #pragma unroll
  for (int i = 0; i < 4; ++i) {
    const int r = i * 32 + (tid >> 3);
    int ra = bm + r; if (ra > 1599) ra = 1599;     // tail clamp
    arow[i] = ra;
    awofs[i] = r * 64 + akseg * 8;           // LDS byte offset (8B per seg)
  }

  // ---- compute geometry: 2x2 waves, wave tile 64x64
  const int wm = wid >> 1, wn = wid & 1;
  const int r15 = lane & 15, q = lane >> 4;
  const int aoff = (wm * 64 + r15) * 64 + q * 16;
  const int boff = (wn * 64 + r15) * 64 + q * 16;

  v4f acc[4][4];
  #pragma unroll
  for (int i = 0; i < 4; ++i)
    #pragma unroll
    for (int j = 0; j < 4; ++j) acc[i][j] = (v4f)(0.f);

  auto stageB = [&](int buf, int kt) {
    const int kb = kt * 64;                  // 32 bf16 = 64B per K-step
    #pragma unroll
    for (int i = 0; i < 2; ++i) {
      GLL(gwh + srcB[i] + kb, &smem[buf][2][ldsoff[i]]);
      GLL(gwl + srcB[i] + kb, &smem[buf][3][ldsoff[i]]);
    }
  };

  float4 a4[4];

  // prologue: stage tile 0
  #pragma unroll
  for (int i = 0; i < 4; ++i)
    a4[i] = *(const float4*)&A[(size_t)arow[i] * RD_ + akseg * 4];
  stageB(0, 0);
  #pragma unroll
  for (int i = 0; i < 4; ++i) {
    uint2 h, l; bsplit4(a4[i], h, l);
    *(uint2*)&smem[0][0][awofs[i]] = h;
    *(uint2*)&smem[0][1][awofs[i]] = l;
  }
  __syncthreads();

  for (int kt = 0; kt < 50; ++kt) {
    const int cur = kt & 1;
    if (kt < 49) {
      stageB(cur ^ 1, kt + 1);
      #pragma unroll
      for (int i = 0; i < 4; ++i)
        a4[i] = *(const float4*)&A[(size_t)arow[i] * RD_ + (kt + 1) * 32 + akseg * 4];
    }
    const char* s0 = &smem[cur][0][0];
    v4f ah[4], al[4], bh[4], bl[4];
    #pragma unroll
    for (int t = 0; t < 4; ++t) {
      ah[t] = *(const v4f*)(s0 +         aoff + t * 1024);
      al[t] = *(const v4f*)(s0 +  8192 + aoff + t * 1024);
      bh[t] = *(const v4f*)(s0 + 16384 + boff + t * 1024);
      bl[t] = *(const v4f*)(s0 + 24576 + boff + t * 1024);
    }
    #pragma unroll
    for (int im = 0; im < 4; ++im)
      #pragma unroll
      for (int in = 0; in < 4; ++in) {
        mfma16(acc[im][in], ah[im], bh[in]);   // hi*hi
        mfma16(acc[im][in], ah[im], bl[in]);   // hi*lo
        mfma16(acc[im][in], al[im], bh[in]);   // lo*hi
      }
    if (kt < 49) {
      const int nxt = cur ^ 1;
      #pragma unroll
      for (int i = 0; i < 4; ++i) {
        uint2 h, l; bsplit4(a4[i], h, l);
        *(uint2*)&smem[nxt][0][awofs[i]] = h;
        *(uint2*)&smem[nxt][1][awofs[i]] = l;
      }
    }
    __syncthreads();
  }

  // C/D layout: col = lane&15, row = (lane>>4)*4 + reg
  const int mb  = bm + wm * 64 + q * 4;
  const int nbq = bn + wn * 64 + r15;
  #pragma unroll
  for (int im = 0; im < 4; ++im) {
    #pragma unroll
    for (int in = 0; in < 4; ++in) {
      const int n = nbq + in * 16;
      const int m0 = mb + im * 16;
      if (n < 1600) {
        #pragma unroll
        for (int r = 0; r < 4; ++r)
          if (m0 + r < 1600)
            C[(size_t)(m0 + r) * RD_ + n] = acc[im][in][r];
      }
    }
  }
}

// ---------------- scan + fused head: one block per b.  (round-0 proven form)
__global__ __launch_bounds__(512, 2) void scan_kernel(
    const float* __restrict__ x,       // [BS_][RD_]
    const float* __restrict__ Wall,    // [BS_][RD_]
    const float* __restrict__ table,   // [NG_*NP_][RD_]
    const float* __restrict__ u0,      // [RD_]
    const float* __restrict__ vkeys,   // [RD_]
    const float* __restrict__ keys,    // [RD_]
    const float* __restrict__ init_state, // [D_]
    const float* __restrict__ alpha_in_p,
    const int*   __restrict__ queries, // [B_][L_]
    const float* __restrict__ emb,     // [V_][D_]
    const float* __restrict__ q_mult,  // [L_][D_]
    const float* __restrict__ Hw,      // [D_][D_]
    const float* __restrict__ alpha_q_p,
    float* __restrict__ h_g)           // [B_][D_]
{
  const int b = blockIdx.x, tid = threadIdx.x;
  __shared__ __align__(16) float s_state[D_];
  __shared__ __align__(16) float s_c[RD_];
  __shared__ float s_hw[D_ * 101];     // Hw padded stride 101 (conflict-free)
  __shared__ unsigned long long s_mask[2];
  const float alpha = alpha_in_p[0];
  const bool active = (tid < 400);
  const int j4 = tid * 4;
  const int d4 = (j4 % D_);
  float4 kk = make_float4(0.f,0.f,0.f,0.f), vv = kk;
  const float* xb = x    + (size_t)b * S_ * RD_;
  const float* wb = Wall + (size_t)b * S_ * RD_;
  v4f bx[5], bw[5];
  #pragma unroll
  for (int i = 0; i < 5; ++i) { bx[i] = (v4f)(0.f); bw[i] = (v4f)(0.f); }
  if (active) {
    kk = *(const float4*)&keys[j4];
    vv = *(const float4*)&vkeys[j4];
    #pragma unroll
    for (int i = 0; i < 5; ++i) {          // preload steps 0..4 (non-temporal)
      bx[i] = NTL(&xb[(size_t)i * RD_ + j4]);
      bw[i] = NTL(&wb[(size_t)i * RD_ + j4]);
    }
  }
  if (tid < D_) s_state[tid] = init_state[tid];
  __syncthreads();

  for (int sg = 0; sg < S_; sg += 5) {
    #pragma unroll
    for (int i = 0; i < 5; ++i) {
      const int s = sg + i;
      if (active) {
        const v4f sent = bx[i], w = bw[i];
        if (s + 5 < S_) {                  // stagger: prefetch step s+5
          bx[i] = NTL(&xb[(size_t)(s + 5) * RD_ + j4]);
          bw[i] = NTL(&wb[(size_t)(s + 5) * RD_ + j4]);
        }
        v4f u;
        if (s == 0) {
          float4 t0 = *(const float4*)&u0[j4];
          u.x = t0.x; u.y = t0.y; u.z = t0.z; u.w = t0.w;
        } else {
          u = (v4f)(0.f);
          const unsigned long long m0 = s_mask[0];
          const unsigned long long m1 = s_mask[1];
          #pragma unroll
          for (int g = 0; g < NG_; ++g) {
            const unsigned idx = (g < 16)
                ? (unsigned)((m0 >> (4 * g)) & 15ull)
                : (unsigned)((m1 >> (4 * g - 64)) & 15ull);
            float4 tv = *(const float4*)&table[((size_t)(g * NP_) + idx) * RD_ + j4];
            u.x += tv.x; u.y += tv.y; u.z += tv.z; u.w += tv.w;
          }
        }
        float4 sd = *(const float4*)&s_state[d4];
        float zx = sent.x * sd.x + sent.x * kk.x;
        float zy = sent.y * sd.y + sent.y * kk.y;
        float zz = sent.z * sd.z + sent.z * kk.z;
        float zw = sent.w * sd.w + sent.w * kk.w;
        float gx = 1.0f / (1.0f + expf(-zx));
        float gy = 1.0f / (1.0f + expf(-zy));
        float gz = 1.0f / (1.0f + expf(-zz));
        float gw = 1.0f / (1.0f + expf(-zw));
        float cx = u.x + vv.x + w.x; cx = cx >= 0.f ? cx : alpha * cx;
        float cy = u.y + vv.y + w.y; cy = cy >= 0.f ? cy : alpha * cy;
        float cz = u.z + vv.z + w.z; cz = cz >= 0.f ? cz : alpha * cz;
        float cw = u.w + vv.w + w.w; cw = cw >= 0.f ? cw : alpha * cw;
        v4f cc;
        cc.x = (gx == 0.5f) ? 0.f : cx * gx;
        cc.y = (gy == 0.5f) ? 0.f : cy * gy;
        cc.z = (gz == 0.5f) ? 0.f : cz * gz;
        cc.w = (gw == 0.5f) ? 0.f : cw * gw;
        *(v4f*)&s_c[j4] = cc;
      }
      __syncthreads();
      if (tid < D_) {
        float csum = 0.f;
        #pragma unroll
        for (int r = 0; r < R_; ++r) csum += s_c[r * D_ + tid];
        float v = s_state[tid] + csum;
        v = v / sqrtf(v * v);   // faithful: torch.norm over singleton dim -> sign
        s_state[tid] = v;
        unsigned long long mask = __ballot(v < 0.f);
        if ((tid & 63) == 0) s_mask[tid >> 6] = mask;
      }
      __syncthreads();
    }
  }

  // ---- fused head: h[b][d] = prelu(q[b][d] + dot(state, Hw[d]), alpha_q)
  for (int f = tid; f < D_ * D_; f += 512) {
    const int row = f / D_, col = f - row * D_;
    s_hw[row * 101 + col] = Hw[f];
  }
  __syncthreads();
  if (tid < D_) {
    float q = 0.f;
    #pragma unroll
    for (int l = 0; l < L_; ++l) {
      const int tok = queries[b * L_ + l];
      if (tok != 0) q += emb[(size_t)tok * D_ + tid] * q_mult[l * D_ + tid];
    }
    float a = 0.f;
    #pragma unroll 4
    for (int k = 0; k < D_; ++k) a += s_state[k] * s_hw[tid * 101 + k];
    float h = q + a;
    const float aq = alpha_q_p[0];
    h = h >= 0.f ? h : aq * h;
    h_g[(size_t)b * D_ + tid] = h;
  }
}

// ---------------- out[b][v] = sum_k h[b][k] * Rw[v][k]   (v-tile=32 staged in LDS)
__global__ __launch_bounds__(256) void out_kernel(
    const float* __restrict__ h_g, const float* __restrict__ Rw, float* __restrict__ out)
{
  __shared__ __align__(16) float sh[B_ * D_];    // 3200
  __shared__ __align__(16) float sr[32 * D_];    // 3200
  int tid = threadIdx.x;
  int v0 = blockIdx.x * 32;
  for (int i = tid; i < B_ * D_; i += 256) sh[i] = h_g[i];
  int nrows = V_ - v0; if (nrows > 32) nrows = 32;
  for (int i = tid; i < nrows * D_; i += 256) sr[i] = Rw[(size_t)v0 * D_ + i];
  __syncthreads();
  const float4* sh4 = (const float4*)sh;
  const float4* sr4 = (const float4*)sr;
  int tv = (tid & 15) * 2;
  int tb = (tid >> 4) * 2;
  float a00 = 0.f, a01 = 0.f, a10 = 0.f, a11 = 0.f;
  #pragma unroll
  for (int kc = 0; kc < 25; ++kc) {
    float4 h0 = sh4[tb * 25 + kc];
    float4 h1 = sh4[(tb + 1) * 25 + kc];
    float4 r0 = sr4[tv * 25 + kc];
    float4 r1 = sr4[(tv + 1) * 25 + kc];
    a00 += h0.x*r0.x + h0.y*r0.y + h0.z*r0.z + h0.w*r0.w;
    a01 += h0.x*r1.x + h0.y*r1.y + h0.z*r1.z + h0.w*r1.w;
    a10 += h1.x*r0.x + h1.y*r0.y + h1.z*r0.z + h1.w*r0.w;
    a11 += h1.x*r1.x + h1.y*r1.y + h1.z*r1.z + h1.w*r1.w;
  }
  if (tv < nrows) {
    out[(size_t)tb * V_ + v0 + tv] = a00;
    out[(size_t)(tb + 1) * V_ + v0 + tv] = a10;
  }
  if (tv + 1 < nrows) {
    out[(size_t)tb * V_ + v0 + tv + 1] = a01;
    out[(size_t)(tb + 1) * V_ + v0 + tv + 1] = a11;
  }
}

extern "C" void kernel_launch(void* const* d_in, const int* in_sizes, int n_in,
                              void* d_out, int out_size, void* d_ws, size_t ws_size,
                              hipStream_t stream) {
  const int*   stories    = (const int*)  d_in[0];
  const int*   queries    = (const int*)  d_in[1];
  const float* emb        = (const float*)d_in[2];
  const float* in_mult    = (const float*)d_in[3];
  const float* q_mult     = (const float*)d_in[4];
  const float* keys       = (const float*)d_in[5];
  const float* init_state = (const float*)d_in[6];
  const float* U          = (const float*)d_in[7];
  const float* Vw         = (const float*)d_in[8];
  const float* Ww         = (const float*)d_in[9];
  const float* Hw         = (const float*)d_in[10];
  const float* Rw         = (const float*)d_in[11];
  const float* alpha_in   = (const float*)d_in[12];
  const float* alpha_q    = (const float*)d_in[13];
  float* out = (float*)d_out;

  char* ws = (char*)d_ws;
  float* x     = (float*)(ws);               // 10,240,000 B (fp32 x, scan path)
  float* Wall  = (float*)(ws + 10240000);    // 10,240,000 B
  float* table = (float*)(ws + 20480000);    //  2,560,000 B (25*16*1600*4)
  u16*   wwh   = (u16*)  (ws + 23040000);    //  5,120,000 B (bf16 hi of Ww)
  u16*   wwl   = (u16*)  (ws + 28160000);    //  5,120,000 B (bf16 lo of Ww)
  float* vk    = (float*)(ws + 33280000);    //      6,400 B
  float* u0    = (float*)(ws + 33286400);    //      6,400 B
  float* hbuf  = (float*)(ws + 33292800);    //     12,800 B
  // total 33,305,600 B (identical footprint)

  setup_kernel<<<3025, 512, 0, stream>>>(stories, emb, in_mult, U, Vw, keys,
                                         init_state, Ww, x, wwh, wwl,
                                         table, vk, u0);
  gemm_mfma_kernel<<<dim3(13, 13), 256, 0, stream>>>(x, wwh, wwl, Wall);
  scan_kernel<<<B_, 512, 0, stream>>>(x, Wall, table, u0, vk, keys, init_state,
                                      alpha_in, queries, emb, q_mult, Hw, alpha_q,
                                      hbuf);
  out_kernel<<<(V_ + 31) / 32, 256, 0, stream>>>(hbuf, Rw, out);
}

// Round 3
// 370.944 us; speedup vs baseline: 1.2327x; 1.0413x over previous
//
#include <hip/hip_runtime.h>
#include <cstddef>
#include <cstdint>

#define B_  32
#define S_  50
#define L_  20
#define R_  16
#define D_  100
#define V_  50000
#define T_  320       // L_*R_
#define RD_ 1600      // R_*D_
#define BS_ 1600      // B_*S_
#define NG_ 25        // sign-table groups (4 bits each)
#define NP_ 16        // patterns per group

typedef float v4f __attribute__((ext_vector_type(4)));
typedef unsigned short u16;

__device__ __forceinline__ float uf(unsigned u) { return __uint_as_float(u); }

// split fp32 into bf16 hi (truncate) + bf16 lo (residual); hi+lo ~ a to 2^-16 rel
__device__ __forceinline__ void bsplit(float a, unsigned& h, unsigned& l) {
  const unsigned bits = __float_as_uint(a);
  const unsigned hb = bits & 0xffff0000u;
  h = hb >> 16;
  l = __float_as_uint(a - __uint_as_float(hb)) >> 16;
}

__device__ __forceinline__ void bsplit4(float4 a, uint2& h, uint2& l) {
  unsigned h0,h1,h2,h3,l0,l1,l2,l3;
  bsplit(a.x, h0, l0); bsplit(a.y, h1, l1);
  bsplit(a.z, h2, l2); bsplit(a.w, h3, l3);
  h.x = h0 | (h1 << 16); h.y = h2 | (h3 << 16);
  l.x = l0 | (l1 << 16); l.y = l2 | (l3 << 16);
}

// ---------------- fused setup:
// blocks [0,1600): x[bs][j] = sum_l emb0[stories]*in_mult   (fp32, scan-friendly)
// blocks [1600,2000): sign table from U (4-bit)
// blocks [2000,2200): vkeys (8 waves -> 8 j's per block)
// blocks [2200,2400): u0 = U @ init_state
// blocks [2400,3025): Ww -> bf16 hi/lo planes (8 elems/thread)
__global__ __launch_bounds__(512) void setup_kernel(
    const int* __restrict__ stories, const float* __restrict__ emb,
    const float* __restrict__ in_mult, const float* __restrict__ U,
    const float* __restrict__ Vw, const float* __restrict__ keys,
    const float* __restrict__ init_state, const float* __restrict__ Ww,
    float* __restrict__ x,
    u16* __restrict__ wh, u16* __restrict__ wl,
    float* __restrict__ table, float* __restrict__ vk, float* __restrict__ u0)
{
  const int blk = blockIdx.x, tid = threadIdx.x;
  if (blk < 1600) {
    __shared__ int toks[T_];
    const int* st = stories + (size_t)blk * T_;
    if (tid < T_) toks[tid] = st[tid];
    __syncthreads();
    if (tid < 400) {
      const int j4 = tid * 4;
      const int r  = j4 / D_;
      const int d4 = j4 - r * D_;
      float4 acc = make_float4(0.f, 0.f, 0.f, 0.f);
      #pragma unroll
      for (int l = 0; l < 20; ++l) {
        const int t = r * 20 + l;
        const int tok = toks[t];
        if (tok != 0) {
          float4 e = *(const float4*)&emb[(size_t)tok * D_ + d4];
          float4 m = *(const float4*)&in_mult[(size_t)t * D_ + d4];
          acc.x += e.x * m.x; acc.y += e.y * m.y;
          acc.z += e.z * m.z; acc.w += e.w * m.w;
        }
      }
      *(float4*)&x[(size_t)blk * RD_ + j4] = acc;
    }
  } else if (blk < 2000) {
    const int q = blk - 1600;
    const int g = q >> 4, p = q & 15;
    const float s0 = (p & 1) ? -1.f : 1.f;
    const float s1 = (p & 2) ? -1.f : 1.f;
    const float s2 = (p & 4) ? -1.f : 1.f;
    const float s3 = (p & 8) ? -1.f : 1.f;
    if (tid < 400) {
      const int j4 = tid * 4;
      float t[4];
      #pragma unroll
      for (int jj = 0; jj < 4; ++jj) {
        const float* ur = &U[(size_t)(j4 + jj) * D_ + 4 * g];
        t[jj] = s0*ur[0] + s1*ur[1] + s2*ur[2] + s3*ur[3];
      }
      *(float4*)&table[((size_t)(g * NP_ + p)) * RD_ + j4] =
          make_float4(t[0], t[1], t[2], t[3]);
    }
  } else if (blk < 2200) {
    const int wave = tid >> 6, lane = tid & 63;
    const int j = (blk - 2000) * 8 + wave;
    float acc = 0.f;
    for (int k = lane; k < RD_; k += 64)
      acc += keys[k] * Vw[(size_t)j * RD_ + k];
    #pragma unroll
    for (int off = 32; off > 0; off >>= 1) acc += __shfl_down(acc, off);
    if (lane == 0) vk[j] = acc;
  } else if (blk < 2400) {
    const int wave = tid >> 6, lane = tid & 63;
    const int j = (blk - 2200) * 8 + wave;
    const float* Ur = U + (size_t)j * D_;
    float acc = Ur[lane] * init_state[lane];
    if (lane < 36) acc += Ur[64 + lane] * init_state[64 + lane];
    #pragma unroll
    for (int off = 32; off > 0; off >>= 1) acc += __shfl_down(acc, off);
    if (lane == 0) u0[j] = acc;
  } else {
    // Ww -> bf16 hi/lo: 625 blocks * 512 thr * 8 elems = 2,560,000
    const int e = ((blk - 2400) * 512 + tid) * 8;
    float4 a0 = *(const float4*)&Ww[e];
    float4 a1 = *(const float4*)&Ww[e + 4];
    uint2 h0, l0, h1, l1;
    bsplit4(a0, h0, l0);
    bsplit4(a1, h1, l1);
    uint4 hv = make_uint4(h0.x, h0.y, h1.x, h1.y);
    uint4 lv = make_uint4(l0.x, l0.y, l1.x, l1.y);
    *(uint4*)&wh[e] = hv;
    *(uint4*)&wl[e] = lv;
  }
}

// ---------------- bf16x3 MFMA GEMM: Wall[m][n] = sum_k x[m][k]*Ww[n][k]
// A: fp32 x, reg-staged + in-kernel bf16 hi/lo split -> LDS.
// B: pre-converted bf16 planes staged with global_load_lds(16B).
// 128x128 tile, BK=32, 8 waves (2x4 grid, 64x32 wave tile -> 2 waves/SIMD),
// double-buffered LDS. Grid 13x13 (tail clamped). Numerics identical to the
// 4-wave version (same tile, same K order, same per-acc MFMA chain).
typedef const __attribute__((address_space(1))) unsigned GAu;
typedef __attribute__((address_space(3))) unsigned LDSu;
#define GLL(SRC, DST) __builtin_amdgcn_global_load_lds((GAu*)(SRC), (LDSu*)(DST), 16, 0, 0)

__device__ __forceinline__ void mfma16(v4f& d, v4f a, v4f b) {
  asm("v_mfma_f32_16x16x32_bf16 %0, %1, %2, %0" : "+v"(d) : "v"(a), "v"(b));
}

__global__ __launch_bounds__(512) void gemm_mfma_kernel(
    const float* __restrict__ A,
    const u16* __restrict__ wh, const u16* __restrict__ wl,
    float* __restrict__ C)
{
  // [buf][arr: Ah,Al,Bh,Bl][128 rows * 64B] = 64 KiB
  __shared__ __align__(16) char smem[2][4][8192];
  const int tid = threadIdx.x;
  const int lane = tid & 63, wid = tid >> 6;   // 8 waves
  const int bm = blockIdx.y * 128, bn = blockIdx.x * 128;

  // ---- B staging (global_load_lds): wave wid stages rows [wid*16, wid*16+16)
  const int brow = wid * 16 + (lane >> 2);
  const int bkb  = (lane & 3) * 16;            // byte offset within 64B k-row
  int rb = bn + brow; if (rb > 1599) rb = 1599;     // tail clamp
  const int srcB = rb * 3200 + bkb;            // row stride 1600*2B
  const int ldsB = wid * 1024;
  const char* gwh = (const char*)wh;
  const char* gwl = (const char*)wl;

  // ---- A staging (reg-staged fp32 -> bf16 split): 2 segments/thread
  int arow[2], awofs[2];
  const int akseg = tid & 7;
  #pragma unroll
  for (int i = 0; i < 2; ++i) {
    const int r = i * 64 + (tid >> 3);
    int ra = bm + r; if (ra > 1599) ra = 1599;      // tail clamp
    arow[i] = ra;
    awofs[i] = r * 64 + akseg * 8;           // LDS byte offset (8B per seg)
  }

  // ---- compute geometry: wave grid 2(M) x 4(N), wave tile 64x32
  const int wm = wid >> 2, wn = wid & 3;
  const int r15 = lane & 15, q = lane >> 4;
  const int aoff = (wm * 64 + r15) * 64 + q * 16;
  const int boff = (wn * 32 + r15) * 64 + q * 16;

  v4f acc[4][2];
  #pragma unroll
  for (int i = 0; i < 4; ++i)
    #pragma unroll
    for (int j = 0; j < 2; ++j) acc[i][j] = (v4f)(0.f);

  auto stageB = [&](int buf, int kt) {
    const int kb = kt * 64;                  // 32 bf16 = 64B per K-step
    GLL(gwh + srcB + kb, &smem[buf][2][ldsB]);
    GLL(gwl + srcB + kb, &smem[buf][3][ldsB]);
  };

  float4 a4[2];

  // prologue: stage tile 0
  #pragma unroll
  for (int i = 0; i < 2; ++i)
    a4[i] = *(const float4*)&A[(size_t)arow[i] * RD_ + akseg * 4];
  stageB(0, 0);
  #pragma unroll
  for (int i = 0; i < 2; ++i) {
    uint2 h, l; bsplit4(a4[i], h, l);
    *(uint2*)&smem[0][0][awofs[i]] = h;
    *(uint2*)&smem[0][1][awofs[i]] = l;
  }
  __syncthreads();

  for (int kt = 0; kt < 50; ++kt) {
    const int cur = kt & 1;
    if (kt < 49) {
      stageB(cur ^ 1, kt + 1);
      #pragma unroll
      for (int i = 0; i < 2; ++i)
        a4[i] = *(const float4*)&A[(size_t)arow[i] * RD_ + (kt + 1) * 32 + akseg * 4];
    }
    const char* s0 = &smem[cur][0][0];
    v4f ah[4], al[4], bh[2], bl[2];
    #pragma unroll
    for (int t = 0; t < 4; ++t) {
      ah[t] = *(const v4f*)(s0 +         aoff + t * 1024);
      al[t] = *(const v4f*)(s0 +  8192 + aoff + t * 1024);
    }
    #pragma unroll
    for (int t = 0; t < 2; ++t) {
      bh[t] = *(const v4f*)(s0 + 16384 + boff + t * 1024);
      bl[t] = *(const v4f*)(s0 + 24576 + boff + t * 1024);
    }
    #pragma unroll
    for (int im = 0; im < 4; ++im)
      #pragma unroll
      for (int in = 0; in < 2; ++in) {
        mfma16(acc[im][in], ah[im], bh[in]);   // hi*hi
        mfma16(acc[im][in], ah[im], bl[in]);   // hi*lo
        mfma16(acc[im][in], al[im], bh[in]);   // lo*hi
      }
    if (kt < 49) {
      const int nxt = cur ^ 1;
      #pragma unroll
      for (int i = 0; i < 2; ++i) {
        uint2 h, l; bsplit4(a4[i], h, l);
        *(uint2*)&smem[nxt][0][awofs[i]] = h;
        *(uint2*)&smem[nxt][1][awofs[i]] = l;
      }
    }
    __syncthreads();
  }

  // C/D layout: col = lane&15, row = (lane>>4)*4 + reg
  const int mb  = bm + wm * 64 + q * 4;
  const int nbq = bn + wn * 32 + r15;
  #pragma unroll
  for (int im = 0; im < 4; ++im) {
    #pragma unroll
    for (int in = 0; in < 2; ++in) {
      const int n = nbq + in * 16;
      const int m0 = mb + im * 16;
      if (n < 1600) {
        #pragma unroll
        for (int r = 0; r < 4; ++r)
          if (m0 + r < 1600)
            C[(size_t)(m0 + r) * RD_ + n] = acc[im][in][r];
      }
    }
  }
}

// ---------------- scan + fused head: one block per b.
// Per-step op order matters: the 25 mask-dependent table gathers (L2) are
// issued FIRST; the x/Wall stream prefetch is pinned BELOW all table
// consumption via sched_barrier(0). vmcnt retires in issue order, so older
// in-flight stream loads would otherwise force a full HBM-latency drain on
// every table wait. Stream loads are plain (not NT): x/Wall are L3-resident
// (just written by setup/gemm) and table's touch rate keeps it L2-hot.
__global__ __launch_bounds__(512, 2) void scan_kernel(
    const float* __restrict__ x,       // [BS_][RD_]
    const float* __restrict__ Wall,    // [BS_][RD_]
    const float* __restrict__ table,   // [NG_*NP_][RD_]
    const float* __restrict__ u0,      // [RD_]
    const float* __restrict__ vkeys,   // [RD_]
    const float* __restrict__ keys,    // [RD_]
    const float* __restrict__ init_state, // [D_]
    const float* __restrict__ alpha_in_p,
    const int*   __restrict__ queries, // [B_][L_]
    const float* __restrict__ emb,     // [V_][D_]
    const float* __restrict__ q_mult,  // [L_][D_]
    const float* __restrict__ Hw,      // [D_][D_]
    const float* __restrict__ alpha_q_p,
    float* __restrict__ h_g)           // [B_][D_]
{
  const int b = blockIdx.x, tid = threadIdx.x;
  __shared__ __align__(16) float s_state[D_];
  __shared__ __align__(16) float s_c[RD_];
  __shared__ float s_hw[D_ * 101];     // Hw padded stride 101 (conflict-free)
  __shared__ unsigned long long s_mask[2];
  const float alpha = alpha_in_p[0];
  const bool active = (tid < 400);
  const int j4 = tid * 4;
  const int d4 = (j4 % D_);
  float4 kk = make_float4(0.f,0.f,0.f,0.f), vv = kk;
  const float* xb = x    + (size_t)b * S_ * RD_;
  const float* wb = Wall + (size_t)b * S_ * RD_;
  v4f bx[5], bw[5];
  #pragma unroll
  for (int i = 0; i < 5; ++i) { bx[i] = (v4f)(0.f); bw[i] = (v4f)(0.f); }
  if (active) {
    kk = *(const float4*)&keys[j4];
    vv = *(const float4*)&vkeys[j4];
    #pragma unroll
    for (int i = 0; i < 5; ++i) {          // preload steps 0..4
      bx[i] = *(const v4f*)&xb[(size_t)i * RD_ + j4];
      bw[i] = *(const v4f*)&wb[(size_t)i * RD_ + j4];
    }
  }
  if (tid < D_) s_state[tid] = init_state[tid];
  __syncthreads();

  for (int sg = 0; sg < S_; sg += 5) {
    #pragma unroll
    for (int i = 0; i < 5; ++i) {
      const int s = sg + i;
      if (active) {
        const v4f sent = bx[i], w = bw[i];
        // ---- 1. u: mask-dependent table gathers issued first (L2-resident)
        v4f u;
        if (s == 0) {
          float4 t0 = *(const float4*)&u0[j4];
          u.x = t0.x; u.y = t0.y; u.z = t0.z; u.w = t0.w;
        } else {
          u = (v4f)(0.f);
          const unsigned long long m0 = s_mask[0];
          const unsigned long long m1 = s_mask[1];
          #pragma unroll
          for (int g = 0; g < NG_; ++g) {
            const unsigned idx = (g < 16)
                ? (unsigned)((m0 >> (4 * g)) & 15ull)
                : (unsigned)((m1 >> (4 * g - 64)) & 15ull);
            float4 tv = *(const float4*)&table[((size_t)(g * NP_) + idx) * RD_ + j4];
            u.x += tv.x; u.y += tv.y; u.z += tv.z; u.w += tv.w;
          }
        }
        // ---- 2. gate math (independent of u; fills table-load shadow)
        float4 sd = *(const float4*)&s_state[d4];
        float zx = sent.x * sd.x + sent.x * kk.x;
        float zy = sent.y * sd.y + sent.y * kk.y;
        float zz = sent.z * sd.z + sent.z * kk.z;
        float zw = sent.w * sd.w + sent.w * kk.w;
        float gx = 1.0f / (1.0f + expf(-zx));
        float gy = 1.0f / (1.0f + expf(-zy));
        float gz = 1.0f / (1.0f + expf(-zz));
        float gw = 1.0f / (1.0f + expf(-zw));
        float cx = u.x + vv.x + w.x; cx = cx >= 0.f ? cx : alpha * cx;
        float cy = u.y + vv.y + w.y; cy = cy >= 0.f ? cy : alpha * cy;
        float cz = u.z + vv.z + w.z; cz = cz >= 0.f ? cz : alpha * cz;
        float cw = u.w + vv.w + w.w; cw = cw >= 0.f ? cw : alpha * cw;
        v4f cc;
        cc.x = (gx == 0.5f) ? 0.f : cx * gx;
        cc.y = (gy == 0.5f) ? 0.f : cy * gy;
        cc.z = (gz == 0.5f) ? 0.f : cz * gz;
        cc.w = (gw == 0.5f) ? 0.f : cw * gw;
        // ---- 3. stream prefetch pinned below all table consumption
        __builtin_amdgcn_sched_barrier(0);
        if (s + 5 < S_) {                  // stagger: prefetch step s+5
          bx[i] = *(const v4f*)&xb[(size_t)(s + 5) * RD_ + j4];
          bw[i] = *(const v4f*)&wb[(size_t)(s + 5) * RD_ + j4];
        }
        *(v4f*)&s_c[j4] = cc;
      }
      __syncthreads();
      if (tid < D_) {
        float csum = 0.f;
        #pragma unroll
        for (int r = 0; r < R_; ++r) csum += s_c[r * D_ + tid];
        float v = s_state[tid] + csum;
        v = v / sqrtf(v * v);   // faithful: torch.norm over singleton dim -> sign
        s_state[tid] = v;
        unsigned long long mask = __ballot(v < 0.f);
        if ((tid & 63) == 0) s_mask[tid >> 6] = mask;
      }
      __syncthreads();
    }
  }

  // ---- fused head: h[b][d] = prelu(q[b][d] + dot(state, Hw[d]), alpha_q)
  for (int f = tid; f < D_ * D_; f += 512) {
    const int row = f / D_, col = f - row * D_;
    s_hw[row * 101 + col] = Hw[f];
  }
  __syncthreads();
  if (tid < D_) {
    float q = 0.f;
    #pragma unroll
    for (int l = 0; l < L_; ++l) {
      const int tok = queries[b * L_ + l];
      if (tok != 0) q += emb[(size_t)tok * D_ + tid] * q_mult[l * D_ + tid];
    }
    float a = 0.f;
    #pragma unroll 4
    for (int k = 0; k < D_; ++k) a += s_state[k] * s_hw[tid * 101 + k];
    float h = q + a;
    const float aq = alpha_q_p[0];
    h = h >= 0.f ? h : aq * h;
    h_g[(size_t)b * D_ + tid] = h;
  }
}

// ---------------- out[b][v] = sum_k h[b][k] * Rw[v][k]   (v-tile=32 staged in LDS)
__global__ __launch_bounds__(256) void out_kernel(
    const float* __restrict__ h_g, const float* __restrict__ Rw, float* __restrict__ out)
{
  __shared__ __align__(16) float sh[B_ * D_];    // 3200
  __shared__ __align__(16) float sr[32 * D_];    // 3200
  int tid = threadIdx.x;
  int v0 = blockIdx.x * 32;
  for (int i = tid; i < B_ * D_; i += 256) sh[i] = h_g[i];
  int nrows = V_ - v0; if (nrows > 32) nrows = 32;
  for (int i = tid; i < nrows * D_; i += 256) sr[i] = Rw[(size_t)v0 * D_ + i];
  __syncthreads();
  const float4* sh4 = (const float4*)sh;
  const float4* sr4 = (const float4*)sr;
  int tv = (tid & 15) * 2;
  int tb = (tid >> 4) * 2;
  float a00 = 0.f, a01 = 0.f, a10 = 0.f, a11 = 0.f;
  #pragma unroll
  for (int kc = 0; kc < 25; ++kc) {
    float4 h0 = sh4[tb * 25 + kc];
    float4 h1 = sh4[(tb + 1) * 25 + kc];
    float4 r0 = sr4[tv * 25 + kc];
    float4 r1 = sr4[(tv + 1) * 25 + kc];
    a00 += h0.x*r0.x + h0.y*r0.y + h0.z*r0.z + h0.w*r0.w;
    a01 += h0.x*r1.x + h0.y*r1.y + h0.z*r1.z + h0.w*r1.w;
    a10 += h1.x*r0.x + h1.y*r0.y + h1.z*r0.z + h1.w*r0.w;
    a11 += h1.x*r1.x + h1.y*r1.y + h1.z*r1.z + h1.w*r1.w;
  }
  if (tv < nrows) {
    out[(size_t)tb * V_ + v0 + tv] = a00;
    out[(size_t)(tb + 1) * V_ + v0 + tv] = a10;
  }
  if (tv + 1 < nrows) {
    out[(size_t)tb * V_ + v0 + tv + 1] = a01;
    out[(size_t)(tb + 1) * V_ + v0 + tv + 1] = a11;
  }
}

extern "C" void kernel_launch(void* const* d_in, const int* in_sizes, int n_in,
                              void* d_out, int out_size, void* d_ws, size_t ws_size,
                              hipStream_t stream) {
  const int*   stories    = (const int*)  d_in[0];
  const int*   queries    = (const int*)  d_in[1];
  const float* emb        = (const float*)d_in[2];
  const float* in_mult    = (const float*)d_in[3];
  const float* q_mult     = (const float*)d_in[4];
  const float* keys       = (const float*)d_in[5];
  const float* init_state = (const float*)d_in[6];
  const float* U          = (const float*)d_in[7];
  const float* Vw         = (const float*)d_in[8];
  const float* Ww         = (const float*)d_in[9];
  const float* Hw         = (const float*)d_in[10];
  const float* Rw         = (const float*)d_in[11];
  const float* alpha_in   = (const float*)d_in[12];
  const float* alpha_q    = (const float*)d_in[13];
  float* out = (float*)d_out;

  char* ws = (char*)d_ws;
  float* x     = (float*)(ws);               // 10,240,000 B (fp32 x, scan path)
  float* Wall  = (float*)(ws + 10240000);    // 10,240,000 B
  float* table = (float*)(ws + 20480000);    //  2,560,000 B (25*16*1600*4)
  u16*   wwh   = (u16*)  (ws + 23040000);    //  5,120,000 B (bf16 hi of Ww)
  u16*   wwl   = (u16*)  (ws + 28160000);    //  5,120,000 B (bf16 lo of Ww)
  float* vk    = (float*)(ws + 33280000);    //      6,400 B
  float* u0    = (float*)(ws + 33286400);    //      6,400 B
  float* hbuf  = (float*)(ws + 33292800);    //     12,800 B
  // total 33,305,600 B (identical footprint)

  setup_kernel<<<3025, 512, 0, stream>>>(stories, emb, in_mult, U, Vw, keys,
                                         init_state, Ww, x, wwh, wwl,
                                         table, vk, u0);
  gemm_mfma_kernel<<<dim3(13, 13), 512, 0, stream>>>(x, wwh, wwl, Wall);
  scan_kernel<<<B_, 512, 0, stream>>>(x, Wall, table, u0, vk, keys, init_state,
                                      alpha_in, queries, emb, q_mult, Hw, alpha_q,
                                      hbuf);
  out_kernel<<<(V_ + 31) / 32, 256, 0, stream>>>(hbuf, Rw, out);
}

// Round 4
// 363.032 us; speedup vs baseline: 1.2595x; 1.0218x over previous
//
#include <hip/hip_runtime.h>
#include <cstddef>
#include <cstdint>

#define B_  32
#define S_  50
#define L_  20
#define R_  16
#define D_  100
#define V_  50000
#define T_  320       // L_*R_
#define RD_ 1600      // R_*D_
#define BS_ 1600      // B_*S_
#define NG_ 25        // sign-table groups (4 bits each)
#define NP_ 16        // patterns per group

typedef float v4f __attribute__((ext_vector_type(4)));
typedef unsigned short u16;
#define NTL(p)  __builtin_nontemporal_load((const v4f*)(p))

__device__ __forceinline__ float uf(unsigned u) { return __uint_as_float(u); }

// split fp32 into bf16 hi (truncate) + bf16 lo (residual); hi+lo ~ a to 2^-16 rel
__device__ __forceinline__ void bsplit(float a, unsigned& h, unsigned& l) {
  const unsigned bits = __float_as_uint(a);
  const unsigned hb = bits & 0xffff0000u;
  h = hb >> 16;
  l = __float_as_uint(a - __uint_as_float(hb)) >> 16;
}

__device__ __forceinline__ void bsplit4(float4 a, uint2& h, uint2& l) {
  unsigned h0,h1,h2,h3,l0,l1,l2,l3;
  bsplit(a.x, h0, l0); bsplit(a.y, h1, l1);
  bsplit(a.z, h2, l2); bsplit(a.w, h3, l3);
  h.x = h0 | (h1 << 16); h.y = h2 | (h3 << 16);
  l.x = l0 | (l1 << 16); l.y = l2 | (l3 << 16);
}

// ---------------- fused setup:
// blocks [0,1600): x[bs][j] = sum_l emb0[stories]*in_mult   (fp32, scan-friendly)
// blocks [1600,2000): sign table from U (4-bit)
// blocks [2000,2200): vkeys (8 waves -> 8 j's per block)
// blocks [2200,2400): u0 = U @ init_state
// blocks [2400,3025): Ww -> bf16 hi/lo planes (8 elems/thread)
__global__ __launch_bounds__(512) void setup_kernel(
    const int* __restrict__ stories, const float* __restrict__ emb,
    const float* __restrict__ in_mult, const float* __restrict__ U,
    const float* __restrict__ Vw, const float* __restrict__ keys,
    const float* __restrict__ init_state, const float* __restrict__ Ww,
    float* __restrict__ x,
    u16* __restrict__ wh, u16* __restrict__ wl,
    float* __restrict__ table, float* __restrict__ vk, float* __restrict__ u0)
{
  const int blk = blockIdx.x, tid = threadIdx.x;
  if (blk < 1600) {
    __shared__ int toks[T_];
    const int* st = stories + (size_t)blk * T_;
    if (tid < T_) toks[tid] = st[tid];
    __syncthreads();
    if (tid < 400) {
      const int j4 = tid * 4;
      const int r  = j4 / D_;
      const int d4 = j4 - r * D_;
      float4 acc = make_float4(0.f, 0.f, 0.f, 0.f);
      #pragma unroll
      for (int l = 0; l < 20; ++l) {
        const int t = r * 20 + l;
        const int tok = toks[t];
        if (tok != 0) {
          float4 e = *(const float4*)&emb[(size_t)tok * D_ + d4];
          float4 m = *(const float4*)&in_mult[(size_t)t * D_ + d4];
          acc.x += e.x * m.x; acc.y += e.y * m.y;
          acc.z += e.z * m.z; acc.w += e.w * m.w;
        }
      }
      *(float4*)&x[(size_t)blk * RD_ + j4] = acc;
    }
  } else if (blk < 2000) {
    const int q = blk - 1600;
    const int g = q >> 4, p = q & 15;
    const float s0 = (p & 1) ? -1.f : 1.f;
    const float s1 = (p & 2) ? -1.f : 1.f;
    const float s2 = (p & 4) ? -1.f : 1.f;
    const float s3 = (p & 8) ? -1.f : 1.f;
    if (tid < 400) {
      const int j4 = tid * 4;
      float t[4];
      #pragma unroll
      for (int jj = 0; jj < 4; ++jj) {
        const float* ur = &U[(size_t)(j4 + jj) * D_ + 4 * g];
        t[jj] = s0*ur[0] + s1*ur[1] + s2*ur[2] + s3*ur[3];
      }
      *(float4*)&table[((size_t)(g * NP_ + p)) * RD_ + j4] =
          make_float4(t[0], t[1], t[2], t[3]);
    }
  } else if (blk < 2200) {
    const int wave = tid >> 6, lane = tid & 63;
    const int j = (blk - 2000) * 8 + wave;
    float acc = 0.f;
    for (int k = lane; k < RD_; k += 64)
      acc += keys[k] * Vw[(size_t)j * RD_ + k];
    #pragma unroll
    for (int off = 32; off > 0; off >>= 1) acc += __shfl_down(acc, off);
    if (lane == 0) vk[j] = acc;
  } else if (blk < 2400) {
    const int wave = tid >> 6, lane = tid & 63;
    const int j = (blk - 2200) * 8 + wave;
    const float* Ur = U + (size_t)j * D_;
    float acc = Ur[lane] * init_state[lane];
    if (lane < 36) acc += Ur[64 + lane] * init_state[64 + lane];
    #pragma unroll
    for (int off = 32; off > 0; off >>= 1) acc += __shfl_down(acc, off);
    if (lane == 0) u0[j] = acc;
  } else {
    // Ww -> bf16 hi/lo: 625 blocks * 512 thr * 8 elems = 2,560,000
    const int e = ((blk - 2400) * 512 + tid) * 8;
    float4 a0 = *(const float4*)&Ww[e];
    float4 a1 = *(const float4*)&Ww[e + 4];
    uint2 h0, l0, h1, l1;
    bsplit4(a0, h0, l0);
    bsplit4(a1, h1, l1);
    uint4 hv = make_uint4(h0.x, h0.y, h1.x, h1.y);
    uint4 lv = make_uint4(l0.x, l0.y, l1.x, l1.y);
    *(uint4*)&wh[e] = hv;
    *(uint4*)&wl[e] = lv;
  }
}

// ---------------- bf16x3 MFMA GEMM: Wall[m][n] = sum_k x[m][k]*Ww[n][k]
// A: fp32 x, reg-staged + in-kernel bf16 hi/lo split -> LDS.
// B: pre-converted bf16 planes staged with global_load_lds(16B).
// 128x128 tile, BK=32, 8 waves (2x4 grid, 64x32 wave tile -> 2 waves/SIMD),
// double-buffered LDS. Grid 13x13 (tail clamped).
typedef const __attribute__((address_space(1))) unsigned GAu;
typedef __attribute__((address_space(3))) unsigned LDSu;
#define GLL(SRC, DST) __builtin_amdgcn_global_load_lds((GAu*)(SRC), (LDSu*)(DST), 16, 0, 0)

__device__ __forceinline__ void mfma16(v4f& d, v4f a, v4f b) {
  asm("v_mfma_f32_16x16x32_bf16 %0, %1, %2, %0" : "+v"(d) : "v"(a), "v"(b));
}

__global__ __launch_bounds__(512) void gemm_mfma_kernel(
    const float* __restrict__ A,
    const u16* __restrict__ wh, const u16* __restrict__ wl,
    float* __restrict__ C)
{
  // [buf][arr: Ah,Al,Bh,Bl][128 rows * 64B] = 64 KiB
  __shared__ __align__(16) char smem[2][4][8192];
  const int tid = threadIdx.x;
  const int lane = tid & 63, wid = tid >> 6;   // 8 waves
  const int bm = blockIdx.y * 128, bn = blockIdx.x * 128;

  // ---- B staging (global_load_lds): wave wid stages rows [wid*16, wid*16+16)
  const int brow = wid * 16 + (lane >> 2);
  const int bkb  = (lane & 3) * 16;            // byte offset within 64B k-row
  int rb = bn + brow; if (rb > 1599) rb = 1599;     // tail clamp
  const int srcB = rb * 3200 + bkb;            // row stride 1600*2B
  const int ldsB = wid * 1024;
  const char* gwh = (const char*)wh;
  const char* gwl = (const char*)wl;

  // ---- A staging (reg-staged fp32 -> bf16 split): 2 segments/thread
  int arow[2], awofs[2];
  const int akseg = tid & 7;
  #pragma unroll
  for (int i = 0; i < 2; ++i) {
    const int r = i * 64 + (tid >> 3);
    int ra = bm + r; if (ra > 1599) ra = 1599;      // tail clamp
    arow[i] = ra;
    awofs[i] = r * 64 + akseg * 8;           // LDS byte offset (8B per seg)
  }

  // ---- compute geometry: wave grid 2(M) x 4(N), wave tile 64x32
  const int wm = wid >> 2, wn = wid & 3;
  const int r15 = lane & 15, q = lane >> 4;
  const int aoff = (wm * 64 + r15) * 64 + q * 16;
  const int boff = (wn * 32 + r15) * 64 + q * 16;

  v4f acc[4][2];
  #pragma unroll
  for (int i = 0; i < 4; ++i)
    #pragma unroll
    for (int j = 0; j < 2; ++j) acc[i][j] = (v4f)(0.f);

  auto stageB = [&](int buf, int kt) {
    const int kb = kt * 64;                  // 32 bf16 = 64B per K-step
    GLL(gwh + srcB + kb, &smem[buf][2][ldsB]);
    GLL(gwl + srcB + kb, &smem[buf][3][ldsB]);
  };

  float4 a4[2];

  // prologue: stage tile 0
  #pragma unroll
  for (int i = 0; i < 2; ++i)
    a4[i] = *(const float4*)&A[(size_t)arow[i] * RD_ + akseg * 4];
  stageB(0, 0);
  #pragma unroll
  for (int i = 0; i < 2; ++i) {
    uint2 h, l; bsplit4(a4[i], h, l);
    *(uint2*)&smem[0][0][awofs[i]] = h;
    *(uint2*)&smem[0][1][awofs[i]] = l;
  }
  __syncthreads();

  for (int kt = 0; kt < 50; ++kt) {
    const int cur = kt & 1;
    if (kt < 49) {
      stageB(cur ^ 1, kt + 1);
      #pragma unroll
      for (int i = 0; i < 2; ++i)
        a4[i] = *(const float4*)&A[(size_t)arow[i] * RD_ + (kt + 1) * 32 + akseg * 4];
    }
    const char* s0 = &smem[cur][0][0];
    v4f ah[4], al[4], bh[2], bl[2];
    #pragma unroll
    for (int t = 0; t < 4; ++t) {
      ah[t] = *(const v4f*)(s0 +         aoff + t * 1024);
      al[t] = *(const v4f*)(s0 +  8192 + aoff + t * 1024);
    }
    #pragma unroll
    for (int t = 0; t < 2; ++t) {
      bh[t] = *(const v4f*)(s0 + 16384 + boff + t * 1024);
      bl[t] = *(const v4f*)(s0 + 24576 + boff + t * 1024);
    }
    #pragma unroll
    for (int im = 0; im < 4; ++im)
      #pragma unroll
      for (int in = 0; in < 2; ++in) {
        mfma16(acc[im][in], ah[im], bh[in]);   // hi*hi
        mfma16(acc[im][in], ah[im], bl[in]);   // hi*lo
        mfma16(acc[im][in], al[im], bh[in]);   // lo*hi
      }
    if (kt < 49) {
      const int nxt = cur ^ 1;
      #pragma unroll
      for (int i = 0; i < 2; ++i) {
        uint2 h, l; bsplit4(a4[i], h, l);
        *(uint2*)&smem[nxt][0][awofs[i]] = h;
        *(uint2*)&smem[nxt][1][awofs[i]] = l;
      }
    }
    __syncthreads();
  }

  // C/D layout: col = lane&15, row = (lane>>4)*4 + reg
  const int mb  = bm + wm * 64 + q * 4;
  const int nbq = bn + wn * 32 + r15;
  #pragma unroll
  for (int im = 0; im < 4; ++im) {
    #pragma unroll
    for (int in = 0; in < 2; ++in) {
      const int n = nbq + in * 16;
      const int m0 = mb + im * 16;
      if (n < 1600) {
        #pragma unroll
        for (int r = 0; r < 4; ++r)
          if (m0 + r < 1600)
            C[(size_t)(m0 + r) * RD_ + n] = acc[im][in][r];
      }
    }
  }
}

// ---------------- scan + fused head: one block per b.
// Occupancy is grid-limited (32 blocks -> 1 block/CU) so VGPRs <=256 are free.
// Per-step issue order (vmcnt retires oldest-first):
//   1. the 25 mask-dependent table gathers -> tv[25] regs  (OLDEST)
//   2. sched_barrier, then NT stream prefetch (x/Wall, 5-step stagger) —
//      younger than gathers, so gather waits never drain the HBM-latency
//      stream loads; NT keeps the 2.56MB table L2-resident.
//   3. gate math (mask-independent) fills the gather-latency shadow.
//   4. u-sum consumes tv, cand/select, LDS store.
__global__ __launch_bounds__(512, 2) void scan_kernel(
    const float* __restrict__ x,       // [BS_][RD_]
    const float* __restrict__ Wall,    // [BS_][RD_]
    const float* __restrict__ table,   // [NG_*NP_][RD_]
    const float* __restrict__ u0,      // [RD_]
    const float* __restrict__ vkeys,   // [RD_]
    const float* __restrict__ keys,    // [RD_]
    const float* __restrict__ init_state, // [D_]
    const float* __restrict__ alpha_in_p,
    const int*   __restrict__ queries, // [B_][L_]
    const float* __restrict__ emb,     // [V_][D_]
    const float* __restrict__ q_mult,  // [L_][D_]
    const float* __restrict__ Hw,      // [D_][D_]
    const float* __restrict__ alpha_q_p,
    float* __restrict__ h_g)           // [B_][D_]
{
  const int b = blockIdx.x, tid = threadIdx.x;
  __shared__ __align__(16) float s_state[D_];
  __shared__ __align__(16) float s_c[RD_];
  __shared__ float s_hw[D_ * 101];     // Hw padded stride 101 (conflict-free)
  __shared__ unsigned long long s_mask[2];
  const float alpha = alpha_in_p[0];
  const bool active = (tid < 400);
  const int j4 = tid * 4;
  const int d4 = (j4 % D_);
  float4 kk = make_float4(0.f,0.f,0.f,0.f), vv = kk;
  const float* xb = x    + (size_t)b * S_ * RD_;
  const float* wb = Wall + (size_t)b * S_ * RD_;
  v4f bx[5], bw[5];
  #pragma unroll
  for (int i = 0; i < 5; ++i) { bx[i] = (v4f)(0.f); bw[i] = (v4f)(0.f); }
  if (active) {
    kk = *(const float4*)&keys[j4];
    vv = *(const float4*)&vkeys[j4];
    #pragma unroll
    for (int i = 0; i < 5; ++i) {          // preload steps 0..4 (non-temporal)
      bx[i] = NTL(&xb[(size_t)i * RD_ + j4]);
      bw[i] = NTL(&wb[(size_t)i * RD_ + j4]);
    }
  }
  if (tid < D_) s_state[tid] = init_state[tid];
  __syncthreads();

  for (int sg = 0; sg < S_; sg += 5) {
    #pragma unroll
    for (int i = 0; i < 5; ++i) {
      const int s = sg + i;
      if (active) {
        const v4f sent = bx[i], w = bw[i];
        const bool first = (s == 0);
        // ---- 1. issue the mask-dependent gathers FIRST (oldest in queue)
        v4f tv[NG_];
        if (first) {
          tv[0] = *(const v4f*)&u0[j4];
        } else {
          const unsigned long long m0 = s_mask[0];
          const unsigned long long m1 = s_mask[1];
          #pragma unroll
          for (int g = 0; g < NG_; ++g) {
            const unsigned idx = (g < 16)
                ? (unsigned)((m0 >> (4 * g)) & 15ull)
                : (unsigned)((m1 >> (4 * g - 64)) & 15ull);
            tv[g] = *(const v4f*)&table[((size_t)(g * NP_) + idx) * RD_ + j4];
          }
        }
        __builtin_amdgcn_sched_barrier(0);
        // ---- 2. stream prefetch (younger than gathers; NT protects L2)
        if (s + 5 < S_) {
          bx[i] = NTL(&xb[(size_t)(s + 5) * RD_ + j4]);
          bw[i] = NTL(&wb[(size_t)(s + 5) * RD_ + j4]);
        }
        // ---- 3. gate math (independent of gathers; fills load shadow)
        float4 sd = *(const float4*)&s_state[d4];
        float zx = sent.x * sd.x + sent.x * kk.x;
        float zy = sent.y * sd.y + sent.y * kk.y;
        float zz = sent.z * sd.z + sent.z * kk.z;
        float zw = sent.w * sd.w + sent.w * kk.w;
        float gx = 1.0f / (1.0f + expf(-zx));
        float gy = 1.0f / (1.0f + expf(-zy));
        float gz = 1.0f / (1.0f + expf(-zz));
        float gw = 1.0f / (1.0f + expf(-zw));
        // ---- 4. consume gathers (linear sum: numerics identical to prior)
        v4f u = tv[0];
        if (!first) {
          #pragma unroll
          for (int g = 1; g < NG_; ++g) {
            u.x += tv[g].x; u.y += tv[g].y; u.z += tv[g].z; u.w += tv[g].w;
          }
        }
        float cx = u.x + vv.x + w.x; cx = cx >= 0.f ? cx : alpha * cx;
        float cy = u.y + vv.y + w.y; cy = cy >= 0.f ? cy : alpha * cy;
        float cz = u.z + vv.z + w.z; cz = cz >= 0.f ? cz : alpha * cz;
        float cw = u.w + vv.w + w.w; cw = cw >= 0.f ? cw : alpha * cw;
        v4f cc;
        cc.x = (gx == 0.5f) ? 0.f : cx * gx;
        cc.y = (gy == 0.5f) ? 0.f : cy * gy;
        cc.z = (gz == 0.5f) ? 0.f : cz * gz;
        cc.w = (gw == 0.5f) ? 0.f : cw * gw;
        *(v4f*)&s_c[j4] = cc;
      }
      __syncthreads();
      if (tid < D_) {
        float csum = 0.f;
        #pragma unroll
        for (int r = 0; r < R_; ++r) csum += s_c[r * D_ + tid];
        float v = s_state[tid] + csum;
        v = v / sqrtf(v * v);   // faithful: torch.norm over singleton dim -> sign
        s_state[tid] = v;
        unsigned long long mask = __ballot(v < 0.f);
        if ((tid & 63) == 0) s_mask[tid >> 6] = mask;
      }
      __syncthreads();
    }
  }

  // ---- fused head: h[b][d] = prelu(q[b][d] + dot(state, Hw[d]), alpha_q)
  for (int f = tid; f < D_ * D_; f += 512) {
    const int row = f / D_, col = f - row * D_;
    s_hw[row * 101 + col] = Hw[f];
  }
  __syncthreads();
  if (tid < D_) {
    float q = 0.f;
    #pragma unroll
    for (int l = 0; l < L_; ++l) {
      const int tok = queries[b * L_ + l];
      if (tok != 0) q += emb[(size_t)tok * D_ + tid] * q_mult[l * D_ + tid];
    }
    float a = 0.f;
    #pragma unroll 4
    for (int k = 0; k < D_; ++k) a += s_state[k] * s_hw[tid * 101 + k];
    float h = q + a;
    const float aq = alpha_q_p[0];
    h = h >= 0.f ? h : aq * h;
    h_g[(size_t)b * D_ + tid] = h;
  }
}

// ---------------- out[b][v] = sum_k h[b][k] * Rw[v][k]   (v-tile=32 staged in LDS)
__global__ __launch_bounds__(256) void out_kernel(
    const float* __restrict__ h_g, const float* __restrict__ Rw, float* __restrict__ out)
{
  __shared__ __align__(16) float sh[B_ * D_];    // 3200
  __shared__ __align__(16) float sr[32 * D_];    // 3200
  int tid = threadIdx.x;
  int v0 = blockIdx.x * 32;
  for (int i = tid; i < B_ * D_; i += 256) sh[i] = h_g[i];
  int nrows = V_ - v0; if (nrows > 32) nrows = 32;
  for (int i = tid; i < nrows * D_; i += 256) sr[i] = Rw[(size_t)v0 * D_ + i];
  __syncthreads();
  const float4* sh4 = (const float4*)sh;
  const float4* sr4 = (const float4*)sr;
  int tv = (tid & 15) * 2;
  int tb = (tid >> 4) * 2;
  float a00 = 0.f, a01 = 0.f, a10 = 0.f, a11 = 0.f;
  #pragma unroll
  for (int kc = 0; kc < 25; ++kc) {
    float4 h0 = sh4[tb * 25 + kc];
    float4 h1 = sh4[(tb + 1) * 25 + kc];
    float4 r0 = sr4[tv * 25 + kc];
    float4 r1 = sr4[(tv + 1) * 25 + kc];
    a00 += h0.x*r0.x + h0.y*r0.y + h0.z*r0.z + h0.w*r0.w;
    a01 += h0.x*r1.x + h0.y*r1.y + h0.z*r1.z + h0.w*r1.w;
    a10 += h1.x*r0.x + h1.y*r0.y + h1.z*r0.z + h1.w*r0.w;
    a11 += h1.x*r1.x + h1.y*r1.y + h1.z*r1.z + h1.w*r1.w;
  }
  if (tv < nrows) {
    out[(size_t)tb * V_ + v0 + tv] = a00;
    out[(size_t)(tb + 1) * V_ + v0 + tv] = a10;
  }
  if (tv + 1 < nrows) {
    out[(size_t)tb * V_ + v0 + tv + 1] = a01;
    out[(size_t)(tb + 1) * V_ + v0 + tv + 1] = a11;
  }
}

extern "C" void kernel_launch(void* const* d_in, const int* in_sizes, int n_in,
                              void* d_out, int out_size, void* d_ws, size_t ws_size,
                              hipStream_t stream) {
  const int*   stories    = (const int*)  d_in[0];
  const int*   queries    = (const int*)  d_in[1];
  const float* emb        = (const float*)d_in[2];
  const float* in_mult    = (const float*)d_in[3];
  const float* q_mult     = (const float*)d_in[4];
  const float* keys       = (const float*)d_in[5];
  const float* init_state = (const float*)d_in[6];
  const float* U          = (const float*)d_in[7];
  const float* Vw         = (const float*)d_in[8];
  const float* Ww         = (const float*)d_in[9];
  const float* Hw         = (const float*)d_in[10];
  const float* Rw         = (const float*)d_in[11];
  const float* alpha_in   = (const float*)d_in[12];
  const float* alpha_q    = (const float*)d_in[13];
  float* out = (float*)d_out;

  char* ws = (char*)d_ws;
  float* x     = (float*)(ws);               // 10,240,000 B (fp32 x, scan path)
  float* Wall  = (float*)(ws + 10240000);    // 10,240,000 B
  float* table = (float*)(ws + 20480000);    //  2,560,000 B (25*16*1600*4)
  u16*   wwh   = (u16*)  (ws + 23040000);    //  5,120,000 B (bf16 hi of Ww)
  u16*   wwl   = (u16*)  (ws + 28160000);    //  5,120,000 B (bf16 lo of Ww)
  float* vk    = (float*)(ws + 33280000);    //      6,400 B
  float* u0    = (float*)(ws + 33286400);    //      6,400 B
  float* hbuf  = (float*)(ws + 33292800);    //     12,800 B
  // total 33,305,600 B (identical footprint)

  setup_kernel<<<3025, 512, 0, stream>>>(stories, emb, in_mult, U, Vw, keys,
                                         init_state, Ww, x, wwh, wwl,
                                         table, vk, u0);
  gemm_mfma_kernel<<<dim3(13, 13), 512, 0, stream>>>(x, wwh, wwl, Wall);
  scan_kernel<<<B_, 512, 0, stream>>>(x, Wall, table, u0, vk, keys, init_state,
                                      alpha_in, queries, emb, q_mult, Hw, alpha_q,
                                      hbuf);
  out_kernel<<<(V_ + 31) / 32, 256, 0, stream>>>(hbuf, Rw, out);
}